// Round 1
// baseline (724.499 us; speedup 1.0000x reference)
//
#include <hip/hip_runtime.h>

#define EPSF 1e-8f

// One block per batch row b (B=8192). Row layout: p[b] = [E=8][C=1000] fp32.
// Output row = 8029 floats: [8000 raw p][8 entropy][8 confidence][8 margin]
//                           [disagree][mean_kl][mix_ent][post_var][mutual_info]
__global__ __launch_bounds__(256, 4) void gating_feat_kernel(
    const float* __restrict__ pin, float* __restrict__ out)
{
    const int b = blockIdx.x;
    const int t = threadIdx.x;
    const size_t inb = (size_t)b * 8000;
    const size_t ob  = (size_t)b * 8029;

    // per-thread accumulators (neutral values for lanes t>=250)
    float plogp[8], mx1[8], mx2[8];
    int   am[8];
#pragma unroll
    for (int e = 0; e < 8; ++e) {
        plogp[e] = 0.f; mx1[e] = -3.0e38f; mx2[e] = -3.0e38f; am[e] = 0x7fffffff;
    }
    float cross = 0.f;   // sum over c, over pairs i<j of p_i[c]*logp_j[c]
    float mixent = 0.f;  // sum over c of m*log(m+eps), m = mean over experts
    float varacc = 0.f;  // sum over c of (sum_e p^2 - 8*m^2)   (divide by 7*1000 later)

    if (t < 250) {
        // 250 threads * 4 classes = 1000 classes; float4 loads are 16B-aligned
        float pr[8][4];
#pragma unroll
        for (int e = 0; e < 8; ++e) {
            const float4 v = *(const float4*)(pin + inb + e * 1000 + 4 * t);
            pr[e][0] = v.x; pr[e][1] = v.y; pr[e][2] = v.z; pr[e][3] = v.w;
        }
        // raw copy to out (row pitch 8029 breaks 16B alignment -> dword stores)
#pragma unroll
        for (int e = 0; e < 8; ++e) {
            const size_t o = ob + e * 1000 + 4 * t;
            out[o + 0] = pr[e][0]; out[o + 1] = pr[e][1];
            out[o + 2] = pr[e][2]; out[o + 3] = pr[e][3];
        }
#pragma unroll
        for (int k = 0; k < 4; ++k) {
            const int c = 4 * t + k;
            float prefix = 0.f, ss = 0.f;
#pragma unroll
            for (int e = 0; e < 8; ++e) {
                const float pv = pr[e][k];
                const float lp = __logf(pv + EPSF);
                plogp[e] += pv * lp;
                // running top-2 + argmax (strict '>' keeps first index; c increases)
                if (pv > mx1[e]) { mx2[e] = mx1[e]; mx1[e] = pv; am[e] = c; }
                else if (pv > mx2[e]) { mx2[e] = pv; }
                // prefix trick: sum_{i<j} p_i*lp_j without the ExE matrix
                cross += prefix * lp;
                prefix += pv;
                ss += pv * pv;
            }
            const float m = prefix * 0.125f;       // mixture mean
            mixent += m * __logf(m + EPSF);
            varacc += ss - 8.f * m * m;            // (ddof=1 divide deferred)
        }
    }

    // ---- intra-wave reduction (64 lanes) ----
#pragma unroll
    for (int off = 32; off >= 1; off >>= 1) {
#pragma unroll
        for (int e = 0; e < 8; ++e) {
            plogp[e] += __shfl_down(plogp[e], off);
            const float o1 = __shfl_down(mx1[e], off);
            const float o2 = __shfl_down(mx2[e], off);
            const int   oa = __shfl_down(am[e], off);
            if (o1 > mx1[e])       { mx2[e] = fmaxf(mx1[e], o2); mx1[e] = o1; am[e] = oa; }
            else if (o1 == mx1[e]) { mx2[e] = mx1[e]; if (oa < am[e]) am[e] = oa; }
            else                   { mx2[e] = fmaxf(mx2[e], o1); }
        }
        cross  += __shfl_down(cross,  off);
        mixent += __shfl_down(mixent, off);
        varacc += __shfl_down(varacc, off);
    }

    // ---- cross-wave merge via tiny LDS ----
    __shared__ float sf[4][27];
    __shared__ int   si[4][8];
    const int wave = t >> 6;
    const int lane = t & 63;
    if (lane == 0) {
#pragma unroll
        for (int e = 0; e < 8; ++e) {
            sf[wave][e]      = plogp[e];
            sf[wave][8 + e]  = mx1[e];
            sf[wave][16 + e] = mx2[e];
            si[wave][e]      = am[e];
        }
        sf[wave][24] = cross; sf[wave][25] = mixent; sf[wave][26] = varacc;
    }
    __syncthreads();

    if (t == 0) {
        for (int w = 1; w < 4; ++w) {
#pragma unroll
            for (int e = 0; e < 8; ++e) {
                plogp[e] += sf[w][e];
                const float o1 = sf[w][8 + e], o2 = sf[w][16 + e];
                const int   oa = si[w][e];
                if (o1 > mx1[e])       { mx2[e] = fmaxf(mx1[e], o2); mx1[e] = o1; am[e] = oa; }
                else if (o1 == mx1[e]) { mx2[e] = mx1[e]; if (oa < am[e]) am[e] = oa; }
                else                   { mx2[e] = fmaxf(mx2[e], o1); }
            }
            cross += sf[w][24]; mixent += sf[w][25]; varacc += sf[w][26];
        }

        float sum_plogp = 0.f, wsum = 0.f;
#pragma unroll
        for (int e = 0; e < 8; ++e) {
            sum_plogp += plogp[e];
            wsum += (float)(7 - e) * plogp[e];      // sum_{i<j} plogp_i
            out[ob + 8000 + e] = -plogp[e];         // expert_entropy
            out[ob + 8008 + e] = mx1[e];            // expert_confidence
            out[ob + 8016 + e] = mx1[e] - mx2[e];   // expert_margin
        }
        // unique argmax classes among 8 experts
        int nu = 0;
        for (int i = 0; i < 8; ++i) {
            bool u = true;
            for (int j = 0; j < i; ++j) if (am[j] == am[i]) u = false;
            nu += u ? 1 : 0;
        }
        out[ob + 8024] = (float)(nu - 1) * (1.f / 7.f);          // disagreement_ratio
        out[ob + 8025] = (wsum - cross) * (1.f / 28.f);          // mean_pairwise_kl
        const float me = -mixent;
        out[ob + 8026] = me;                                     // mixture_entropy
        out[ob + 8027] = varacc * (1.f / 7000.f);                // post_var (ddof=1, /C)
        out[ob + 8028] = me + sum_plogp * 0.125f;                // mutual_info
    }
}

extern "C" void kernel_launch(void* const* d_in, const int* in_sizes, int n_in,
                              void* d_out, int out_size, void* d_ws, size_t ws_size,
                              hipStream_t stream) {
    const float* p = (const float*)d_in[0];
    float* out = (float*)d_out;
    const int B = in_sizes[0] / 8000;   // 8192
    gating_feat_kernel<<<B, 256, 0, stream>>>(p, out);
}

// Round 2
// 509.436 us; speedup vs baseline: 1.4222x; 1.4222x over previous
//
#include <hip/hip_runtime.h>

#define EPSF 1e-8f

// One block per batch row b (B=8192). Row layout: p[b] = [E=8][C=1000] fp32.
// Output row = 8029 floats: [8000 raw p][8 entropy][8 confidence][8 margin]
//                           [disagree][mean_kl][mix_ent][post_var][mutual_info]
//
// Thread t (t<250) owns classes {t, t+250, t+500, t+750}: every global load
// and store instruction is lane-contiguous (64 consecutive dwords = 256 B),
// eliminating the 1.7x HBM write amplification of the strided-store layout.
__global__ __launch_bounds__(256, 4) void gating_feat_kernel(
    const float* __restrict__ pin, float* __restrict__ out)
{
    const int b = blockIdx.x;
    const int t = threadIdx.x;
    const size_t inb = (size_t)b * 8000;
    const size_t ob  = (size_t)b * 8029;

    // per-thread accumulators (neutral values for lanes t>=250)
    float plogp[8], mx1[8], mx2[8];
    int   am[8];
#pragma unroll
    for (int e = 0; e < 8; ++e) {
        plogp[e] = 0.f; mx1[e] = -3.0e38f; mx2[e] = -3.0e38f; am[e] = 0x7fffffff;
    }
    float cross = 0.f;   // sum over c, over pairs i<j of p_i[c]*logp_j[c]
    float mixent = 0.f;  // sum over c of m*log(m+eps), m = mean over experts
    float varacc = 0.f;  // sum over c of (sum_e p^2 - 8*m^2)  (/(7*1000) later)

    if (t < 250) {
        float pr[8][4];
        // lane-contiguous loads: addr = inb + e*1000 + k*250 + t
#pragma unroll
        for (int e = 0; e < 8; ++e)
#pragma unroll
            for (int k = 0; k < 4; ++k)
                pr[e][k] = pin[inb + e * 1000 + k * 250 + t];
        // raw copy to out, same lane-contiguous pattern
#pragma unroll
        for (int e = 0; e < 8; ++e)
#pragma unroll
            for (int k = 0; k < 4; ++k)
                out[ob + e * 1000 + k * 250 + t] = pr[e][k];

#pragma unroll
        for (int k = 0; k < 4; ++k) {
            const int c = k * 250 + t;   // ascending in k per thread
            float prefix = 0.f, ss = 0.f;
#pragma unroll
            for (int e = 0; e < 8; ++e) {
                const float pv = pr[e][k];
                const float lp = __logf(pv + EPSF);
                plogp[e] += pv * lp;
                // running top-2 + argmax (strict '>' keeps first/lowest c)
                if (pv > mx1[e]) { mx2[e] = mx1[e]; mx1[e] = pv; am[e] = c; }
                else if (pv > mx2[e]) { mx2[e] = pv; }
                // prefix trick: sum_{i<j} p_i*lp_j without the ExE matrix
                cross += prefix * lp;
                prefix += pv;
                ss += pv * pv;
            }
            const float m = prefix * 0.125f;       // mixture mean
            mixent += m * __logf(m + EPSF);
            varacc += ss - 8.f * m * m;            // (ddof=1 divide deferred)
        }
    }

    // ---- intra-wave reduction (64 lanes) ----
#pragma unroll
    for (int off = 32; off >= 1; off >>= 1) {
#pragma unroll
        for (int e = 0; e < 8; ++e) {
            plogp[e] += __shfl_down(plogp[e], off);
            const float o1 = __shfl_down(mx1[e], off);
            const float o2 = __shfl_down(mx2[e], off);
            const int   oa = __shfl_down(am[e], off);
            if (o1 > mx1[e])       { mx2[e] = fmaxf(mx1[e], o2); mx1[e] = o1; am[e] = oa; }
            else if (o1 == mx1[e]) { mx2[e] = mx1[e]; if (oa < am[e]) am[e] = oa; }
            else                   { mx2[e] = fmaxf(mx2[e], o1); }
        }
        cross  += __shfl_down(cross,  off);
        mixent += __shfl_down(mixent, off);
        varacc += __shfl_down(varacc, off);
    }

    // ---- cross-wave merge via tiny LDS ----
    __shared__ float sf[4][27];
    __shared__ int   si[4][8];
    const int wave = t >> 6;
    const int lane = t & 63;
    if (lane == 0) {
#pragma unroll
        for (int e = 0; e < 8; ++e) {
            sf[wave][e]      = plogp[e];
            sf[wave][8 + e]  = mx1[e];
            sf[wave][16 + e] = mx2[e];
            si[wave][e]      = am[e];
        }
        sf[wave][24] = cross; sf[wave][25] = mixent; sf[wave][26] = varacc;
    }
    __syncthreads();

    if (t == 0) {
        for (int w = 1; w < 4; ++w) {
#pragma unroll
            for (int e = 0; e < 8; ++e) {
                plogp[e] += sf[w][e];
                const float o1 = sf[w][8 + e], o2 = sf[w][16 + e];
                const int   oa = si[w][e];
                if (o1 > mx1[e])       { mx2[e] = fmaxf(mx1[e], o2); mx1[e] = o1; am[e] = oa; }
                else if (o1 == mx1[e]) { mx2[e] = mx1[e]; if (oa < am[e]) am[e] = oa; }
                else                   { mx2[e] = fmaxf(mx2[e], o1); }
            }
            cross += sf[w][24]; mixent += sf[w][25]; varacc += sf[w][26];
        }

        float sum_plogp = 0.f, wsum = 0.f;
#pragma unroll
        for (int e = 0; e < 8; ++e) {
            sum_plogp += plogp[e];
            wsum += (float)(7 - e) * plogp[e];      // sum_{i<j} plogp_i
            out[ob + 8000 + e] = -plogp[e];         // expert_entropy
            out[ob + 8008 + e] = mx1[e];            // expert_confidence
            out[ob + 8016 + e] = mx1[e] - mx2[e];   // expert_margin
        }
        // unique argmax classes among 8 experts
        int nu = 0;
        for (int i = 0; i < 8; ++i) {
            bool u = true;
            for (int j = 0; j < i; ++j) if (am[j] == am[i]) u = false;
            nu += u ? 1 : 0;
        }
        out[ob + 8024] = (float)(nu - 1) * (1.f / 7.f);          // disagreement_ratio
        out[ob + 8025] = (wsum - cross) * (1.f / 28.f);          // mean_pairwise_kl
        const float me = -mixent;
        out[ob + 8026] = me;                                     // mixture_entropy
        out[ob + 8027] = varacc * (1.f / 7000.f);                // post_var (ddof=1, /C)
        out[ob + 8028] = me + sum_plogp * 0.125f;                // mutual_info
    }
}

extern "C" void kernel_launch(void* const* d_in, const int* in_sizes, int n_in,
                              void* d_out, int out_size, void* d_ws, size_t ws_size,
                              hipStream_t stream) {
    const float* p = (const float*)d_in[0];
    float* out = (float*)d_out;
    const int B = in_sizes[0] / 8000;   // 8192
    gating_feat_kernel<<<B, 256, 0, stream>>>(p, out);
}